// Round 5
// baseline (129.211 us; speedup 1.0000x reference)
//
#include <hip/hip_runtime.h>
#include <hip/hip_cooperative_groups.h>
#include <math.h>

namespace cg = cooperative_groups;

#define EPSF 1e-6f

__device__ __forceinline__ float fexp2(float x) {
    return __builtin_amdgcn_exp2f(x);   // v_exp_f32
}

// ============ shared phase logic (used by both coop + fallback) ============

// Phase A body: point i in [0,2n); writes pts[i] and 6-wide block partials.
__device__ __forceinline__ void phaseA_body(
        const float* __restrict__ src, const float* __restrict__ tgt, int n,
        int i, int tid, float4* __restrict__ pts, double* __restrict__ prepP,
        int pslot, double red[4][6]) {
    const float* p = (i < n) ? (src + 3 * i) : (tgt + 3 * (i - n));
    float x = p[0], y = p[1], z = p[2];
    float phi = 2.f * x + y + 1.f / (z + EPSF);
    float dphi = phi - 18.f;
    float w = expf(-(dphi * dphi) * (1.f / 128.f));
    pts[i] = make_float4(x, y, z, w);
    double acc[6];
    acc[0] = (double)(x * x + y * y + z * z);
    acc[1] = (double)x; acc[2] = (double)y; acc[3] = (double)z;
    acc[4] = (i < n) ? (double)w : 0.0;
    acc[5] = (i < n) ? 0.0 : (double)w;
    #pragma unroll
    for (int k = 0; k < 6; ++k) {
        double v = acc[k];
        for (int off = 32; off > 0; off >>= 1) v += __shfl_down(v, off);
        if ((tid & 63) == 0) red[tid >> 6][k] = v;
    }
    __syncthreads();
    if (tid < 6)
        prepP[pslot * 6 + tid] = red[0][tid] + red[1][tid] + red[2][tid] + red[3][tid];
}

// Bandwidth scalar from the 32 prep partials (closed form, f64).
__device__ __forceinline__ float bw_scalar(const double* __restrict__ prepP, int n) {
    double S0 = 0, Sx = 0, Sy = 0, Sz = 0;
    for (int b = 0; b < 32; ++b) {
        S0 += prepP[b * 6 + 0];
        Sx += prepP[b * 6 + 1];
        Sy += prepP[b * 6 + 2];
        Sz += prepP[b * 6 + 3];
    }
    double ntf = 2.0 * (double)n;
    double sumL2 = 2.0 * ntf * S0 - 2.0 * (Sx * Sx + Sy * Sy + Sz * Sz);
    double bw = sumL2 / (ntf * ntf - ntf) * 0.25;   // / KERNEL_MUL^(5//2)
    return (float)(-1.4426950408889634 / bw);       // term_i = exp2(d*m*2^-i)
}

// Phase B body: one block = (source chunk bx of 256 rows) x (target chunk by
// of 256 cols). Stages 256 targets in LDS; returns block partial (f64).
__device__ __forceinline__ double phaseB_body(
        const float4* __restrict__ pts, int n, float m,
        int bx, int by, int tid, float4* tg, double wsum[4]) {
    tg[tid] = pts[n + (by << 8) + tid];
    __syncthreads();
    float4 sp = pts[(bx << 8) + tid];
    float a0 = 0.f;
    #pragma unroll 8
    for (int j = 0; j < 256; ++j) {
        float4 t = tg[j];                           // uniform idx -> LDS broadcast
        float dx = sp.x - t.x, dy = sp.y - t.y, dz = sp.z - t.z;
        float d = dx * dx + dy * dy + dz * dz;
        float u = d * m;
        float k = fexp2(u) + fexp2(u * 0.5f) + fexp2(u * 0.25f)
                + fexp2(u * 0.125f) + fexp2(u * 0.0625f);
        a0 += t.w * k;
    }
    double v = (double)(a0 * sp.w);
    for (int off = 32; off > 0; off >>= 1) v += __shfl_down(v, off);
    if ((tid & 63) == 0) wsum[tid >> 6] = v;
    __syncthreads();
    return wsum[0] + wsum[1] + wsum[2] + wsum[3];
}

// Phase C body: block 0 sums 256 main partials + normalizes.
__device__ __forceinline__ void phaseC_body(
        const double* __restrict__ prepP, const double* __restrict__ mainP,
        int tid, double wsum[4], float* __restrict__ out) {
    double a = mainP[tid];
    for (int off = 32; off > 0; off >>= 1) a += __shfl_down(a, off);
    if ((tid & 63) == 0) wsum[tid >> 6] = a;
    __syncthreads();
    if (tid == 0) {
        double tot = wsum[0] + wsum[1] + wsum[2] + wsum[3];
        double Sw = 0, Tw = 0;
        for (int b = 0; b < 32; ++b) {
            Sw += prepP[b * 6 + 4];
            Tw += prepP[b * 6 + 5];
        }
        out[0] = (float)(-2.0 * tot / ((Sw + (double)EPSF) * (Tw + (double)EPSF)));
    }
}

// ============ cooperative fused kernel: 256 blocks (1/CU guaranteed) ============
__global__ __launch_bounds__(256) void fused256(
    const float* __restrict__ src, const float* __restrict__ tgt, int n,
    float4* __restrict__ pts, double* __restrict__ prepP,
    double* __restrict__ mainP, float* __restrict__ out)
{
    cg::grid_group grid = cg::this_grid();
    const int tid = threadIdx.x;
    const int bid = blockIdx.x;

    __shared__ double red[4][6];
    __shared__ float4 tg[256];
    __shared__ double wsum[4];

    if (bid < 32)
        phaseA_body(src, tgt, n, bid * 256 + tid, tid, pts, prepP, bid, red);

    grid.sync();

    float m = bw_scalar(prepP, n);
    double part = phaseB_body(pts, n, m, bid >> 4, bid & 15, tid, tg, wsum);
    if (tid == 0) mainP[bid] = part;

    grid.sync();

    if (bid == 0) {
        __syncthreads();                 // wsum reuse barrier
        phaseC_body(prepP, mainP, tid, wsum, out);
    }
}

// ============ fallback: 3 plain dispatches (no memset, no atomics) ============
__global__ __launch_bounds__(256) void prep2(
    const float* __restrict__ src, const float* __restrict__ tgt, int n,
    float4* __restrict__ pts, double* __restrict__ prepP) {
    __shared__ double red[4][6];
    phaseA_body(src, tgt, n, blockIdx.x * 256 + threadIdx.x, threadIdx.x,
                pts, prepP, blockIdx.x, red);
}

__global__ __launch_bounds__(256) void main2(
    const float4* __restrict__ pts, int n,
    const double* __restrict__ prepP, double* __restrict__ mainP) {
    __shared__ float4 tg[256];
    __shared__ double wsum[4];
    float m = bw_scalar(prepP, n);
    double part = phaseB_body(pts, n, m, blockIdx.x, blockIdx.y,
                              threadIdx.x, tg, wsum);
    if (threadIdx.x == 0) mainP[blockIdx.y * 16 + blockIdx.x] = part;
}

__global__ __launch_bounds__(256) void fin2(
    const double* __restrict__ prepP, const double* __restrict__ mainP,
    float* __restrict__ out) {
    __shared__ double wsum[4];
    phaseC_body(prepP, mainP, threadIdx.x, wsum, out);
}

extern "C" void kernel_launch(void* const* d_in, const int* in_sizes, int n_in,
                              void* d_out, int out_size, void* d_ws, size_t ws_size,
                              hipStream_t stream) {
    const float* src = (const float*)d_in[0];
    const float* tgt = (const float*)d_in[1];
    int n = in_sizes[0] / 3;            // 4096
    float* out = (float*)d_out;

    // ws layout: float4 pts[2n] | double prepP[32*6] | double mainP[256]
    char* ws = (char*)d_ws;
    float4* pts = (float4*)ws;
    size_t off = (size_t)(2 * n) * sizeof(float4);
    double* prepP = (double*)(ws + off);
    off += 32 * 6 * sizeof(double);
    double* mainP = (double*)(ws + off);

    void* args[] = {(void*)&src, (void*)&tgt, (void*)&n, (void*)&pts,
                    (void*)&prepP, (void*)&mainP, (void*)&out};
    hipError_t e = hipLaunchCooperativeKernel((void*)fused256, dim3(256),
                                              dim3(256), args, 0, stream);
    if (e != hipSuccess) {
        (void)hipGetLastError();        // clear sticky error, take plain path
        prep2<<<32, 256, 0, stream>>>(src, tgt, n, pts, prepP);
        main2<<<dim3(16, 16), 256, 0, stream>>>(pts, n, prepP, mainP);
        fin2<<<1, 256, 0, stream>>>(prepP, mainP, out);
    }
}